// Round 6
// baseline (6743.566 us; speedup 1.0000x reference)
//
#include <hip/hip_runtime.h>
#include <hip/hip_bf16.h>
#include <cstdint>
#include <cstddef>

#define D_MODEL 768
#define D_INNER 1536
#define DT_RANK 48
#define D_STATE 16
#define SEQ     1024
#define BATCH   2
#define NROWS   2048      // BATCH*SEQ
#define VOCAB   32000
#define LCHUNK  32
#define NCHUNK  32        // SEQ / LCHUNK
#define CHST    49152     // 3072 channels * 16 states
#define MGRID   768       // 3 blocks/CU x 256 CUs, co-resident by launch_bounds
#define NGRP    48        // barrier groups (16 blocks each)

typedef __hip_bfloat16 bf16;
typedef short bf16x8 __attribute__((ext_vector_type(8)));   // 8 bf16 in 4 VGPRs
typedef float f32x4  __attribute__((ext_vector_type(4)));
struct bf8 { bf16 v[8]; };

// ---------------------------------------------------------------------------
// async global->LDS, 16B per lane. LDS dest = wave-uniform base + lane*16.
__device__ __forceinline__ void async_copy16(void* lds, const void* gp) {
    __builtin_amdgcn_global_load_lds(
        (const __attribute__((address_space(1))) unsigned int*)gp,
        (__attribute__((address_space(3)))       unsigned int*)lds,
        16, 0, 0);
}

// ===========================================================================
// gemm256: 256x256 tile, BK=64, 8 waves, 128 KiB LDS dbuf, 8-phase counted
// vmcnt schedule (T2/T3/T4/T5 + bijective XCD swizzle). UNCHANGED (verified
// rounds 1/3/5, ~100us for the logits shape).
// ===========================================================================

#define LDSP(BUF, AB) (smem + (((BUF)*2 + (AB)) << 15))

#define PHB() do { \
  __builtin_amdgcn_sched_barrier(0); \
  __builtin_amdgcn_s_barrier(); \
  __builtin_amdgcn_sched_barrier(0); \
} while (0)

#define WAIT_VMCNT(n) do { \
  asm volatile("s_waitcnt vmcnt(" #n ")" ::: "memory"); \
  __builtin_amdgcn_sched_barrier(0); \
} while (0)

#define STAGE_A(BUF, H, KT) do { \
  const int ru0_ = (H)*64 + wave*8; \
  const int ru1_ = ru0_ + 128; \
  const bf16* ga0_ = Ag + (size_t)(m0 + ru0_ + (lane >> 3)) * (size_t)K + (size_t)((KT)*64 + swz8); \
  const bf16* ga1_ = Ag + (size_t)(m0 + ru1_ + (lane >> 3)) * (size_t)K + (size_t)((KT)*64 + swz8); \
  async_copy16(LDSP(BUF, 0) + ru0_*128, ga0_); \
  async_copy16(LDSP(BUF, 0) + ru1_*128, ga1_); \
} while (0)

#define STAGE_B(BUF, H, KT) do { \
  const int lb0_ = wave*8, lb1_ = 64 + wave*8; \
  const int rb0_ = ((lb0_ >> 5) << 6) + (H)*32 + (lb0_ & 31); \
  const int rb1_ = ((lb1_ >> 5) << 6) + (H)*32 + (lb1_ & 31); \
  const bf16* gb0_ = Bg + (size_t)(n0 + rb0_ + (lane >> 3)) * (size_t)K + (size_t)((KT)*64 + swz8); \
  const bf16* gb1_ = Bg + (size_t)(n0 + rb1_ + (lane >> 3)) * (size_t)K + (size_t)((KT)*64 + swz8); \
  async_copy16(LDSP(BUF, 1) + rb0_*128, gb0_); \
  async_copy16(LDSP(BUF, 1) + rb1_*128, gb1_); \
} while (0)

#define RDA4(BUF, MH) do { \
  _Pragma("unroll") \
  for (int i2_ = 0; i2_ < 4; ++i2_) { \
    const char* rp_ = LDSP(BUF, 0) + (wr*128 + (MH)*64 + i2_*16 + fm) * 128; \
    a[i2_][0] = *(const bf16x8*)(rp_ + (((kqi    ) ^ fm7) << 4)); \
    a[i2_][1] = *(const bf16x8*)(rp_ + (((4 + kqi) ^ fm7) << 4)); \
  } \
} while (0)

#define RDB4(BUF, NH, DST) do { \
  _Pragma("unroll") \
  for (int j2_ = 0; j2_ < 2; ++j2_) { \
    const char* rp_ = LDSP(BUF, 1) + (wc*64 + (NH)*32 + j2_*16 + fm) * 128; \
    DST[j2_][0] = *(const bf16x8*)(rp_ + (((kqi    ) ^ fm7) << 4)); \
    DST[j2_][1] = *(const bf16x8*)(rp_ + (((4 + kqi) ^ fm7) << 4)); \
  } \
} while (0)

#define QMFMA(MH, NH, BB) do { \
  __builtin_amdgcn_s_setprio(1); \
  _Pragma("unroll") \
  for (int i2_ = 0; i2_ < 4; ++i2_) { \
    _Pragma("unroll") \
    for (int j2_ = 0; j2_ < 2; ++j2_) { \
      acc[(MH)*4 + i2_][(NH)*2 + j2_] = __builtin_amdgcn_mfma_f32_16x16x32_bf16( \
          a[i2_][0], BB[j2_][0], acc[(MH)*4 + i2_][(NH)*2 + j2_], 0, 0, 0); \
      acc[(MH)*4 + i2_][(NH)*2 + j2_] = __builtin_amdgcn_mfma_f32_16x16x32_bf16( \
          a[i2_][1], BB[j2_][1], acc[(MH)*4 + i2_][(NH)*2 + j2_], 0, 0, 0); \
    } \
  } \
  __builtin_amdgcn_s_setprio(0); \
} while (0)

#define ITER(TT, LAST) do { \
  RDA4(0, 0); RDB4(0, 0, b0); \
  STAGE_B(1, 1, (TT) + 1); \
  PHB(); QMFMA(0, 0, b0); PHB(); \
  RDB4(0, 1, b1); \
  if (!(LAST)) STAGE_A(0, 0, (TT) + 2); \
  PHB(); QMFMA(0, 1, b1); PHB(); \
  RDA4(0, 1); \
  if (!(LAST)) STAGE_B(0, 0, (TT) + 2); \
  PHB(); QMFMA(1, 0, b0); PHB(); \
  if (!(LAST)) { STAGE_A(0, 1, (TT) + 2); WAIT_VMCNT(6); } else { WAIT_VMCNT(0); } \
  PHB(); QMFMA(1, 1, b1); PHB(); \
  RDA4(1, 0); RDB4(1, 0, b0); \
  if (!(LAST)) STAGE_B(0, 1, (TT) + 2); \
  PHB(); QMFMA(0, 0, b0); PHB(); \
  RDB4(1, 1, b1); \
  if (!(LAST)) STAGE_A(1, 0, (TT) + 3); \
  PHB(); QMFMA(0, 1, b1); PHB(); \
  RDA4(1, 1); \
  if (!(LAST)) STAGE_B(1, 0, (TT) + 3); \
  PHB(); QMFMA(1, 0, b0); PHB(); \
  if (!(LAST)) { STAGE_A(1, 1, (TT) + 3); WAIT_VMCNT(6); } else { WAIT_VMCNT(0); } \
  PHB(); QMFMA(1, 1, b1); PHB(); \
} while (0)

__global__ __launch_bounds__(512, 2) void gemm256(
    const bf16* __restrict__ Ag, const bf16* __restrict__ Bg,
    float* __restrict__ C, int M, int N, int K, int ntm)
{
    (void)M;
    __shared__ __align__(16) char smem[131072];   // [buf][A/B] 4 x 32KB

    const int cpx  = gridDim.x >> 3;
    const int bid  = blockIdx.x;
    const int wgid = (bid & 7) * cpx + (bid >> 3);
    const int m0 = (wgid % ntm) << 8;
    const int n0 = (wgid / ntm) << 8;

    const int t    = threadIdx.x;
    const int wave = t >> 6, lane = t & 63;
    const int wr = wave >> 2, wc = wave & 3;     // 2 x 4 wave grid
    const int fm  = lane & 15, fm7 = lane & 7;
    const int kqi = lane >> 4;
    const int swz8 = (((lane & 7) ^ ((lane >> 3) & 7)) << 3);
    const int nkt = K >> 6;

    f32x4 acc[8][4];
    #pragma unroll
    for (int i = 0; i < 8; ++i)
        #pragma unroll
        for (int j = 0; j < 4; ++j)
            acc[i][j] = {0.f, 0.f, 0.f, 0.f};

    bf16x8 a[4][2], b0[2][2], b1[2][2];

    STAGE_A(0, 0, 0); STAGE_A(0, 1, 0); STAGE_B(0, 0, 0); STAGE_B(0, 1, 0);
    WAIT_VMCNT(4);
    STAGE_A(1, 0, 1); STAGE_A(1, 1, 1); STAGE_B(1, 0, 1);
    WAIT_VMCNT(6);
    PHB();

    int tt = 0;
    #pragma unroll 1
    for (; tt + 2 < nkt; tt += 2) { ITER(tt, false); }
    ITER(tt, true);

    const int lr = (lane >> 4) * 4;
    const int lc = lane & 15;
    #pragma unroll
    for (int i = 0; i < 8; ++i) {
        #pragma unroll
        for (int j = 0; j < 4; ++j) {
            const size_t base = (size_t)(m0 + wr*128 + i*16 + lr) * N
                              + (size_t)(n0 + wc*64 + j*16 + lc);
            #pragma unroll
            for (int r = 0; r < 4; ++r)
                C[base + (size_t)r * N] = acc[i][j][r];
        }
    }
}

// ===========================================================================
// Hierarchical device-scope grid barrier. ALL observations use RMWs
// (fetch_add), which execute at the coherent point — a plain load poll can be
// served a STALE line by the local (non-cross-XCD-coherent) L2 until
// eviction, which is exactly the ~130us/barrier stall measured in round 5.
// Layout (uints, 32-uint = 128B lines): gcnt[g]@[g*32], gflag[g]@[(48+g)*32],
// cnt@[96*32], gen@[97*32]. gflag/gen are monotonic; gcnt/cnt reset before
// the release RMW that publishes them (ACQ_REL orders the reset first).
// ===========================================================================
#define BAR_UINTS (98 * 32)

__device__ __forceinline__ void gsync(unsigned* bar, unsigned target)
{
    __syncthreads();
    if (threadIdx.x == 0) {
        const int g = blockIdx.x >> 4;             // 48 groups of 16 blocks
        unsigned* gcnt = bar + g * 32;
        unsigned* gflg = bar + (NGRP + g) * 32;
        unsigned* cnt  = bar + 96 * 32;
        unsigned* gen  = bar + 97 * 32;
        __threadfence();
        unsigned a = __hip_atomic_fetch_add(gcnt, 1u, __ATOMIC_ACQ_REL,
                                            __HIP_MEMORY_SCOPE_SYSTEM);
        if (a == 15u) {                            // group leader (last of 16)
            __hip_atomic_store(gcnt, 0u, __ATOMIC_RELAXED,
                               __HIP_MEMORY_SCOPE_SYSTEM);
            unsigned c = __hip_atomic_fetch_add(cnt, 1u, __ATOMIC_ACQ_REL,
                                                __HIP_MEMORY_SCOPE_SYSTEM);
            if (c == (unsigned)(NGRP - 1)) {       // last group -> release all
                __hip_atomic_store(cnt, 0u, __ATOMIC_RELAXED,
                                   __HIP_MEMORY_SCOPE_SYSTEM);
                __hip_atomic_fetch_add(gen, 1u, __ATOMIC_ACQ_REL,
                                       __HIP_MEMORY_SCOPE_SYSTEM);
            } else {
                while (__hip_atomic_fetch_add(gen, 0u, __ATOMIC_ACQ_REL,
                                              __HIP_MEMORY_SCOPE_SYSTEM) < target) {
                    __builtin_amdgcn_s_sleep(7);
                }
            }
            __hip_atomic_fetch_add(gflg, 1u, __ATOMIC_ACQ_REL,
                                   __HIP_MEMORY_SCOPE_SYSTEM);
        } else {
            while (__hip_atomic_fetch_add(gflg, 0u, __ATOMIC_ACQ_REL,
                                          __HIP_MEMORY_SCOPE_SYSTEM) < target) {
                __builtin_amdgcn_s_sleep(7);
            }
        }
        __threadfence();
    }
    __syncthreads();
}

__global__ __launch_bounds__(256) void init_bar_kernel(unsigned* bar) {
    for (int i = threadIdx.x; i < BAR_UINTS; i += 256) bar[i] = 0u;
}

// ===========================================================================
// Shared per-stage device bodies (identical arithmetic to the verified
// round-3/5 kernels).
// ===========================================================================

// 128x128 GEMM tile: C(M,N)=A(M,K@lda)*B(N,K@lda)^T, split-K slice z.
// EPI: 0 = store, 2 = softplus(v + bias[col]).
template<int EPI>
__device__ __forceinline__ void gemm_tile_body(
    const bf16* __restrict__ A, const bf16* __restrict__ B,
    float* __restrict__ C, const float* __restrict__ bias,
    int M, int N, int K, int lda, int ntm, int bx, int z,
    bf16* sA, bf16* sB)
{
    const int m0   = (bx % ntm) * 128;
    const int n0   = (bx / ntm) * 128;
    const int koff = z * K;
    const int t    = threadIdx.x;
    const int wave = t >> 6;
    const int lane = t & 63;
    const int r0 = wave * 16 + (lane >> 2);      // tile row 0..63
    const int c0 = (lane & 3) * 8;               // k element offset 0/8/16/24
    const int wm = (wave & 1) * 64;
    const int wn = (wave >> 1) * 64;
    const int fm = lane & 15;
    const int kq = (lane >> 4) * 8;

    f32x4 acc[4][4];
    #pragma unroll
    for (int i = 0; i < 4; ++i)
        #pragma unroll
        for (int j = 0; j < 4; ++j)
            acc[i][j] = {0.f, 0.f, 0.f, 0.f};

    int nr0 = n0 + r0;      if (nr0 > N - 1) nr0 = N - 1;
    int nr1 = n0 + 64 + r0; if (nr1 > N - 1) nr1 = N - 1;

    const bf16* gA0 = A + (size_t)(m0 + r0)      * lda + koff + c0;
    const bf16* gA1 = A + (size_t)(m0 + 64 + r0) * lda + koff + c0;
    const bf16* gB0 = B + (size_t)nr0 * lda + koff + c0;
    const bf16* gB1 = B + (size_t)nr1 * lda + koff + c0;
    char* lA0 = (char*)sA + wave * 1024;
    char* lA1 = (char*)sA + 4096 + wave * 1024;
    char* lB0 = (char*)sB + wave * 1024;
    char* lB1 = (char*)sB + 4096 + wave * 1024;

    float* Cz = C + (size_t)z * M * N;

    for (int k0 = 0; k0 < K; k0 += 32) {
        async_copy16(lA0, gA0 + k0);
        async_copy16(lA1, gA1 + k0);
        async_copy16(lB0, gB0 + k0);
        async_copy16(lB1, gB1 + k0);
        __syncthreads();

        bf16x8 af[4], bfr[4];
        #pragma unroll
        for (int i = 0; i < 4; ++i) {
            af[i]  = *(const bf16x8*)&sA[(wm + i * 16 + fm) * 32 + kq];
            bfr[i] = *(const bf16x8*)&sB[(wn + i * 16 + fm) * 32 + kq];
        }
        #pragma unroll
        for (int i = 0; i < 4; ++i)
            #pragma unroll
            for (int j = 0; j < 4; ++j)
                acc[i][j] = __builtin_amdgcn_mfma_f32_16x16x32_bf16(
                    af[i], bfr[j], acc[i][j], 0, 0, 0);
        __syncthreads();
    }

    const int lr = (lane >> 4) * 4;
    const int lc = lane & 15;
    #pragma unroll
    for (int i = 0; i < 4; ++i) {
        #pragma unroll
        for (int j = 0; j < 4; ++j) {
            const int col = n0 + wn + j * 16 + lc;
            if (col >= N) continue;
            #pragma unroll
            for (int r = 0; r < 4; ++r) {
                const int row = m0 + wm + i * 16 + lr + r;
                const size_t o = (size_t)row * N + col;
                float v = acc[i][j][r];
                if (EPI == 2) {
                    v += bias[col];
                    v = (v > 15.f) ? v : __logf(1.f + __expf(v));
                    Cz[o] = v;
                } else {
                    Cz[o] = v;
                }
            }
        }
    }
}

__device__ __forceinline__ void rmsnorm_body(
    const float* __restrict__ x, const float* __restrict__ w,
    bf16* __restrict__ out, int row, float* red)
{
    const float* xr = x + (size_t)row * D_MODEL;
    const int t = threadIdx.x;
    float v0 = xr[t], v1 = xr[t + 256], v2 = xr[t + 512];
    float s = v0 * v0 + v1 * v1 + v2 * v2;
    #pragma unroll
    for (int m = 1; m < 64; m <<= 1) s += __shfl_xor(s, m);
    if ((t & 63) == 0) red[t >> 6] = s;
    __syncthreads();
    s = red[0] + red[1] + red[2] + red[3];
    __syncthreads();                 // red reused by next loop iteration
    const float sc = rsqrtf(s * (1.f / 768.f) + 1e-5f);
    bf16* o = out + (size_t)row * D_MODEL;
    o[t]       = __float2bfloat16(v0 * sc * w[t]);
    o[t + 256] = __float2bfloat16(v1 * sc * w[t + 256]);
    o[t + 512] = __float2bfloat16(v2 * sc * w[t + 512]);
}

// out_proj split-K reduce + residual add + rmsnorm -> xn
__device__ __forceinline__ void rrn_body(
    const float* __restrict__ part, float* __restrict__ x,
    const float* __restrict__ w, bf16* __restrict__ out, int row, float* red)
{
    const size_t base = (size_t)row * D_MODEL;
    const int t = threadIdx.x;
    float v0, v1, v2;
    {
        const size_t e0 = base + t, e1 = base + t + 256, e2 = base + t + 512;
        v0 = x[e0] + part[e0] + part[e0 + 1572864] + part[e0 + 3145728] + part[e0 + 4718592];
        v1 = x[e1] + part[e1] + part[e1 + 1572864] + part[e1 + 3145728] + part[e1 + 4718592];
        v2 = x[e2] + part[e2] + part[e2 + 1572864] + part[e2 + 3145728] + part[e2 + 4718592];
    }
    x[base + t]       = v0;
    x[base + t + 256] = v1;
    x[base + t + 512] = v2;
    float s = v0 * v0 + v1 * v1 + v2 * v2;
    #pragma unroll
    for (int m = 1; m < 64; m <<= 1) s += __shfl_xor(s, m);
    if ((t & 63) == 0) red[t >> 6] = s;
    __syncthreads();
    s = red[0] + red[1] + red[2] + red[3];
    __syncthreads();
    const float sc = rsqrtf(s * (1.f / 768.f) + 1e-5f);
    bf16* o = out + base;
    o[t]       = __float2bfloat16(v0 * sc * w[t]);
    o[t + 256] = __float2bfloat16(v1 * sc * w[t + 256]);
    o[t + 512] = __float2bfloat16(v2 * sc * w[t + 512]);
}

__device__ __forceinline__ void cvt8_body(
    const float* __restrict__ src, bf16* __restrict__ dst, int item)
{
    const int i = item * 8;
    const float4 a = *(const float4*)(src + i);
    const float4 b = *(const float4*)(src + i + 4);
    bf8 o;
    o.v[0] = __float2bfloat16(a.x); o.v[1] = __float2bfloat16(a.y);
    o.v[2] = __float2bfloat16(a.z); o.v[3] = __float2bfloat16(a.w);
    o.v[4] = __float2bfloat16(b.x); o.v[5] = __float2bfloat16(b.y);
    o.v[6] = __float2bfloat16(b.z); o.v[7] = __float2bfloat16(b.w);
    *(bf8*)(dst + i) = o;
}

// weight cvt, i in [0, 2*3760128): [layer][ip|xp|dt(pad48->64)|op]
__device__ __forceinline__ void cvtw_body(
    int i, const float* __restrict__ ipw, const float* __restrict__ xpw,
    const float* __restrict__ dtw, const float* __restrict__ opw,
    bf16* __restrict__ wip, bf16* __restrict__ wxp,
    bf16* __restrict__ wdt, bf16* __restrict__ wop)
{
    const int l = (i >= 3760128) ? 1 : 0;
    i -= l * 3760128;
    if (i < 3072 * 768) {
        wip[l * 3072 * 768 + i] = __float2bfloat16(ipw[l * 3072 * 768 + i]);
        return;
    }
    i -= 3072 * 768;
    if (i < 80 * 1536) {
        wxp[l * 80 * 1536 + i] = __float2bfloat16(xpw[l * 80 * 1536 + i]);
        return;
    }
    i -= 80 * 1536;
    if (i < 1536 * 64) {
        const int r = i >> 6, c = i & 63;
        wdt[l * 1536 * 64 + i] = __float2bfloat16(
            c < DT_RANK ? dtw[l * 1536 * DT_RANK + r * DT_RANK + c] : 0.f);
        return;
    }
    i -= 1536 * 64;
    wop[l * 768 * 1536 + i] = __float2bfloat16(opw[l * 768 * 1536 + i]);
}

__device__ __forceinline__ void conv_body(
    int idx, const float* __restrict__ xr, const float* __restrict__ cw,
    const float* __restrict__ cb, float* __restrict__ uf, bf16* __restrict__ ub)
{
    const int di  = idx % D_INNER;
    const int row = idx / D_INNER;
    const int l   = row & (SEQ - 1);
    float acc = cb[di];
    #pragma unroll
    for (int j = 0; j < 4; ++j) {
        const int ll = l - 3 + j;
        if (ll >= 0)
            acc += cw[di * 4 + j] * xr[(size_t)(row - 3 + j) * 3072 + di];
    }
    const float s = acc / (1.f + __expf(-acc));
    uf[idx] = s;
    ub[idx] = __float2bfloat16(s);
}

__device__ __forceinline__ void reduce_xp_body(
    int i, const float* __restrict__ p, float* __restrict__ xdbl,
    bf16* __restrict__ dtraw)
{
    const float v = p[i] + p[i + 163840] + p[i + 327680] + p[i + 491520];
    xdbl[i] = v;
    const int r = i / 80, c = i - r * 80;
    if (c < 64)
        dtraw[(r << 6) + c] = __float2bfloat16(c < DT_RANK ? v : 0.f);
}

__device__ __forceinline__ void scan1_body(
    int bx, int k, const float* __restrict__ delta, const float* __restrict__ u,
    const float* __restrict__ x_dbl, const float* __restrict__ A_log,
    float* __restrict__ P, float* __restrict__ H)
{
    const int n  = threadIdx.x & 15;
    const int g  = threadIdx.x >> 4;
    const int ch = bx * 16 + g;      // 0..3071
    const int b  = ch / D_INNER;
    const int di = ch % D_INNER;
    const int t0 = k * LCHUNK;

    const float An = -__expf(A_log[di * D_STATE + n]);
    const float* drow = delta + ((size_t)b * SEQ + t0) * D_INNER + di;
    const float* urow = u     + ((size_t)b * SEQ + t0) * D_INNER + di;
    const float* xdr  = x_dbl + ((size_t)b * SEQ + t0) * 80;

    float h = 0.f, ap = 1.f;
    #pragma unroll
    for (int t = 0; t < LCHUNK; ++t) {
        const float dv = drow[t * D_INNER];
        const float uv = urow[t * D_INNER];
        const float Bv = xdr[t * 80 + 48 + n];
        const float a  = __expf(dv * An);
        h = a * h + (dv * Bv) * uv;
        ap *= a;
    }
    const size_t o = (size_t)k * CHST + ch * 16 + n;
    P[o] = ap;
    H[o] = h;
}

__device__ __forceinline__ void scan2_body(
    int id, const float* __restrict__ P, const float* __restrict__ H,
    float* __restrict__ Hin)
{
    float h = 0.f;
    #pragma unroll
    for (int k = 0; k < NCHUNK; ++k) {
        const size_t o = (size_t)k * CHST + id;
        Hin[o] = h;
        h = P[o] * h + H[o];
    }
}

__device__ __forceinline__ void scan3_body(
    int bx, int k, const float* __restrict__ delta, const float* __restrict__ u,
    const float* __restrict__ x_dbl, const float* __restrict__ xr,
    const float* __restrict__ A_log, const float* __restrict__ Dp,
    const float* __restrict__ Hin, bf16* __restrict__ yb)
{
    const int n  = threadIdx.x & 15;
    const int g  = threadIdx.x >> 4;
    const int ch = bx * 16 + g;
    const int b  = ch / D_INNER;
    const int di = ch % D_INNER;
    const int t0 = k * LCHUNK;

    const float An = -__expf(A_log[di * D_STATE + n]);
    const float Dv = Dp[di];
    const float* drow = delta + ((size_t)b * SEQ + t0) * D_INNER + di;
    const float* urow = u     + ((size_t)b * SEQ + t0) * D_INNER + di;
    const float* rrow = xr + ((size_t)b * SEQ + t0) * 3072 + D_INNER + di;
    const float* xdr  = x_dbl + ((size_t)b * SEQ + t0) * 80;
    bf16* yrow = yb + ((size_t)b * SEQ + t0) * D_INNER + di;

    float h = Hin[(size_t)k * CHST + ch * 16 + n];
    #pragma unroll
    for (int t = 0; t < LCHUNK; ++t) {
        const float dv = drow[t * D_INNER];
        const float uv = urow[t * D_INNER];
        const float Bv = xdr[t * 80 + 48 + n];
        const float Cv = xdr[t * 80 + 64 + n];
        const float a  = __expf(dv * An);
        h = a * h + (dv * Bv) * uv;
        float p = h * Cv;
        p += __shfl_xor(p, 1);
        p += __shfl_xor(p, 2);
        p += __shfl_xor(p, 4);
        p += __shfl_xor(p, 8);
        if (n == 0) {
            float y = p + uv * Dv;
            const float r = rrow[t * 3072];
            y *= r / (1.f + __expf(-r));       // * silu(res)
            yrow[t * D_INNER] = __float2bfloat16(y);
        }
    }
}

// ===========================================================================
// Megakernel: entire network except logits GEMM. Plain launch, hierarchical
// RMW grid barrier. 768 blocks x 256 threads, __launch_bounds__(256,3) =>
// 3 blocks/CU resident -> barrier cannot deadlock. 22 gsyncs, uniform.
// ===========================================================================
struct MegaParams {
    const int* ids; const float* emb; const float* norm_w;
    const float* ipw; const float* cw; const float* cb; const float* xpw;
    const float* dtw; const float* dtb; const float* alog; const float* Dp;
    const float* opw; const float* nfw;
    bf16* emb_bf; float* x; bf16* xn; bf16* ub; float* xdbl; bf16* dtraw;
    bf16* yb; bf16* wip; bf16* wxp; bf16* wdt; bf16* wop;
    float* xr; float* uf; float* delta; float* Pbuf; float* Hbuf; float* Hin;
    float* xpart; float* opart; unsigned* bar;
};

#define GSYNC() do { ++tgt; gsync(p.bar, tgt); } while (0)

__global__ __launch_bounds__(256, 3) void mamba_mega(MegaParams p)
{
    __shared__ __align__(16) char lds[16384];
    bf16* sA  = (bf16*)lds;            // 8 KB
    bf16* sB  = (bf16*)(lds + 8192);   // 8 KB
    float* red = (float*)lds;          // aliased; stages separated by sync

    const int bid  = blockIdx.x;
    const int gtid = bid * 256 + threadIdx.x;
    const int gstr = MGRID * 256;
    unsigned tgt = 0;

    // ---- S0: emb->bf16, weights->bf16, embedding gather (independent) ----
    for (int i = gtid; i < VOCAB * D_MODEL / 8; i += gstr)
        cvt8_body(p.emb, p.emb_bf, i);
    for (int i = gtid; i < 2 * 3760128; i += gstr)
        cvtw_body(i, p.ipw, p.xpw, p.dtw, p.opw, p.wip, p.wxp, p.wdt, p.wop);
    for (int i = gtid; i < NROWS * 192; i += gstr) {
        const int row = i / 192, c = i - row * 192;
        ((float4*)(p.x + (size_t)row * D_MODEL))[c] =
            ((const float4*)(p.emb + (size_t)p.ids[row] * D_MODEL))[c];
    }
    GSYNC();

    // ---- S1: rmsnorm(x) -> xn ----
    for (int r = bid; r < NROWS; r += MGRID)
        rmsnorm_body(p.x, p.norm_w, p.xn, r, red);
    GSYNC();

    for (int l = 0; l < 2; ++l) {
        const bf16* wip = p.wip + (size_t)l * 3072 * 768;
        const bf16* wxp = p.wxp + (size_t)l * 80 * 1536;
        const bf16* wdt = p.wdt + (size_t)l * 1536 * 64;
        const bf16* wop = p.wop + (size_t)l * 768 * 1536;
        const float* al = p.alog + (size_t)l * D_INNER * D_STATE;

        // in_proj: 384 tiles (2048x3072 @ K=768)
        for (int vb = bid; vb < 384; vb += MGRID)
            gemm_tile_body<0>(p.xn, wip, p.xr, nullptr,
                              NROWS, 3072, D_MODEL, D_MODEL, 16, vb, 0, sA, sB);
        GSYNC();
        // conv + silu
        for (int i = gtid; i < NROWS * D_INNER; i += gstr)
            conv_body(i, p.xr, p.cw + (size_t)l * D_INNER * 4,
                      p.cb + (size_t)l * D_INNER, p.uf, p.ub);
        GSYNC();
        // x_proj split-K x4: 64 virtual tiles
        for (int vb = bid; vb < 64; vb += MGRID)
            gemm_tile_body<0>(p.ub, wxp, p.xpart, nullptr,
                              NROWS, 80, 384, D_INNER, 16, vb & 15, vb >> 4, sA, sB);
        GSYNC();
        for (int i = gtid; i < NROWS * 80; i += gstr)
            reduce_xp_body(i, p.xpart, p.xdbl, p.dtraw);
        GSYNC();
        // dt_proj + softplus: 192 tiles
        for (int vb = bid; vb < 192; vb += MGRID)
            gemm_tile_body<2>(p.dtraw, wdt, p.delta, p.dtb + (size_t)l * D_INNER,
                              NROWS, D_INNER, 64, 64, 16, vb, 0, sA, sB);
        GSYNC();
        // scan pass 1: 6144 virtual blocks (= 768 x 8)
        for (int vb = bid; vb < 192 * NCHUNK; vb += MGRID)
            scan1_body(vb % 192, vb / 192, p.delta, p.uf, p.xdbl, al,
                       p.Pbuf, p.Hbuf);
        GSYNC();
        for (int i = gtid; i < CHST; i += gstr)
            scan2_body(i, p.Pbuf, p.Hbuf, p.Hin);
        GSYNC();
        for (int vb = bid; vb < 192 * NCHUNK; vb += MGRID)
            scan3_body(vb % 192, vb / 192, p.delta, p.uf, p.xdbl, p.xr, al,
                       p.Dp + (size_t)l * D_INNER, p.Hin, p.yb);
        GSYNC();
        // out_proj split-K x4: 384 virtual tiles
        for (int vb = bid; vb < 384; vb += MGRID)
            gemm_tile_body<0>(p.yb, wop, p.opart, nullptr,
                              NROWS, D_MODEL, 384, D_INNER, 16, vb % 96, vb / 96,
                              sA, sB);
        GSYNC();
        // reduce + residual + next (or final) rmsnorm
        const float* w2 = (l == 0) ? (p.norm_w + D_MODEL) : p.nfw;
        for (int r = bid; r < NROWS; r += MGRID)
            rrn_body(p.opart, p.x, w2, p.xn, r, red);
        GSYNC();
    }
}

// ---------------------------------------------------------------------------
extern "C" void kernel_launch(void* const* d_in, const int* in_sizes, int n_in,
                              void* d_out, int out_size, void* d_ws, size_t ws_size,
                              hipStream_t stream)
{
    const int*   ids    = (const int*)  d_in[0];
    const float* emb    = (const float*)d_in[1];
    const float* norm_w = (const float*)d_in[2];
    const float* ipw    = (const float*)d_in[3];
    const float* cw     = (const float*)d_in[4];
    const float* cb     = (const float*)d_in[5];
    const float* xpw    = (const float*)d_in[6];
    const float* dtw    = (const float*)d_in[7];
    const float* dtb    = (const float*)d_in[8];
    const float* alog   = (const float*)d_in[9];
    const float* Dp     = (const float*)d_in[10];
    const float* opw    = (const float*)d_in[11];
    const float* nfw    = (const float*)d_in[12];
    float* out = (float*)d_out;

    // -------- workspace layout (~87 MB) --------
    char* ws = (char*)d_ws;
    bf16*  emb_bf = (bf16*)ws;  ws += (size_t)VOCAB * D_MODEL * 2;
    float* x      = (float*)ws; ws += (size_t)NROWS * D_MODEL * 4;
    bf16*  xn     = (bf16*)ws;  ws += (size_t)NROWS * D_MODEL * 2;
    bf16*  ub     = (bf16*)ws;  ws += (size_t)NROWS * D_INNER * 2;
    float* xdbl   = (float*)ws; ws += (size_t)NROWS * 80 * 4;
    bf16*  dtraw  = (bf16*)ws;  ws += (size_t)NROWS * 64 * 2;
    bf16*  yb     = (bf16*)ws;  ws += (size_t)NROWS * D_INNER * 2;
    bf16*  wip    = (bf16*)ws;  ws += (size_t)2 * 3072 * 768 * 2;
    bf16*  wxp    = (bf16*)ws;  ws += (size_t)2 * 80 * 1536 * 2;
    bf16*  wdt    = (bf16*)ws;  ws += (size_t)2 * 1536 * 64 * 2;
    bf16*  wop    = (bf16*)ws;  ws += (size_t)2 * 768 * 1536 * 2;
    unsigned* gbar = (unsigned*)ws; ws += BAR_UINTS * 4;   // barrier lines

    // -------- big transients live in d_out (262 MB), overwritten by logits --------
    char* ob = (char*)d_out;
    float* xr    = (float*)ob;  ob += (size_t)NROWS * 3072 * 4;      // 25.2 MB
    float* uf    = (float*)ob;  ob += (size_t)NROWS * D_INNER * 4;   // 12.6 MB
    float* delta = (float*)ob;  ob += (size_t)NROWS * D_INNER * 4;   // 12.6 MB
    float* Pbuf  = (float*)ob;  ob += (size_t)NCHUNK * CHST * 4;     //  6.3 MB
    float* Hbuf  = (float*)ob;  ob += (size_t)NCHUNK * CHST * 4;     //  6.3 MB
    float* Hin   = (float*)ob;  ob += (size_t)NCHUNK * CHST * 4;     //  6.3 MB
    float* xpart = (float*)ob;  ob += (size_t)4 * NROWS * 80 * 4;    //  2.6 MB
    float* opart = (float*)ob;  ob += (size_t)4 * NROWS * D_MODEL * 4; // 25.2 MB

    MegaParams mp;
    mp.ids = ids; mp.emb = emb; mp.norm_w = norm_w;
    mp.ipw = ipw; mp.cw = cw; mp.cb = cb; mp.xpw = xpw;
    mp.dtw = dtw; mp.dtb = dtb; mp.alog = alog; mp.Dp = Dp;
    mp.opw = opw; mp.nfw = nfw;
    mp.emb_bf = emb_bf; mp.x = x; mp.xn = xn; mp.ub = ub; mp.xdbl = xdbl;
    mp.dtraw = dtraw; mp.yb = yb; mp.wip = wip; mp.wxp = wxp; mp.wdt = wdt;
    mp.wop = wop; mp.xr = xr; mp.uf = uf; mp.delta = delta; mp.Pbuf = Pbuf;
    mp.Hbuf = Hbuf; mp.Hin = Hin; mp.xpart = xpart; mp.opart = opart;
    mp.bar = gbar;

    init_bar_kernel<<<1, 256, 0, stream>>>(gbar);
    mamba_mega<<<MGRID, 256, 0, stream>>>(mp);

    // logits: (2048x768)(32000x768)^T -> out  [256^2 8-phase kernel, 1000 blocks]
    gemm256<<<8 * 125, 512, 0, stream>>>(xn, emb_bf, out,
                                         NROWS, VOCAB, D_MODEL, 8);
}

// Round 7
// 880.143 us; speedup vs baseline: 7.6619x; 7.6619x over previous
//
#include <hip/hip_runtime.h>
#include <hip/hip_bf16.h>
#include <cstdint>
#include <cstddef>

#define D_MODEL 768
#define D_INNER 1536
#define DT_RANK 48
#define D_STATE 16
#define SEQ     1024
#define BATCH   2
#define NROWS   2048      // BATCH*SEQ
#define VOCAB   32000
#define LCHUNK  32
#define NCHUNK  32        // SEQ / LCHUNK
#define CHST    49152     // 3072 channels * 16 states

typedef __hip_bfloat16 bf16;
typedef short bf16x8 __attribute__((ext_vector_type(8)));   // 8 bf16 in 4 VGPRs
typedef float f32x4  __attribute__((ext_vector_type(4)));
struct bf8 { bf16 v[8]; };

// ---------------------------------------------------------------------------
// async global->LDS, 16B per lane. LDS dest = wave-uniform base + lane*16.
__device__ __forceinline__ void async_copy16(void* lds, const void* gp) {
    __builtin_amdgcn_global_load_lds(
        (const __attribute__((address_space(1))) unsigned int*)gp,
        (__attribute__((address_space(3)))       unsigned int*)lds,
        16, 0, 0);
}

// ===========================================================================
// gemm256: 256x256 tile, BK=64, 8 waves, 128 KiB LDS dbuf, 8-phase counted
// vmcnt schedule (T2/T3/T4/T5 + bijective XCD swizzle). UNCHANGED (verified
// rounds 1/3/5/6, ~100us for the logits shape).
// Requirements: M%256==0, N%256==0, K%128==0, grid % 8 == 0.
// ===========================================================================

#define LDSP(BUF, AB) (smem + (((BUF)*2 + (AB)) << 15))

#define PHB() do { \
  __builtin_amdgcn_sched_barrier(0); \
  __builtin_amdgcn_s_barrier(); \
  __builtin_amdgcn_sched_barrier(0); \
} while (0)

#define WAIT_VMCNT(n) do { \
  asm volatile("s_waitcnt vmcnt(" #n ")" ::: "memory"); \
  __builtin_amdgcn_sched_barrier(0); \
} while (0)

#define STAGE_A(BUF, H, KT) do { \
  const int ru0_ = (H)*64 + wave*8; \
  const int ru1_ = ru0_ + 128; \
  const bf16* ga0_ = Ag + (size_t)(m0 + ru0_ + (lane >> 3)) * (size_t)K + (size_t)((KT)*64 + swz8); \
  const bf16* ga1_ = Ag + (size_t)(m0 + ru1_ + (lane >> 3)) * (size_t)K + (size_t)((KT)*64 + swz8); \
  async_copy16(LDSP(BUF, 0) + ru0_*128, ga0_); \
  async_copy16(LDSP(BUF, 0) + ru1_*128, ga1_); \
} while (0)

#define STAGE_B(BUF, H, KT) do { \
  const int lb0_ = wave*8, lb1_ = 64 + wave*8; \
  const int rb0_ = ((lb0_ >> 5) << 6) + (H)*32 + (lb0_ & 31); \
  const int rb1_ = ((lb1_ >> 5) << 6) + (H)*32 + (lb1_ & 31); \
  const bf16* gb0_ = Bg + (size_t)(n0 + rb0_ + (lane >> 3)) * (size_t)K + (size_t)((KT)*64 + swz8); \
  const bf16* gb1_ = Bg + (size_t)(n0 + rb1_ + (lane >> 3)) * (size_t)K + (size_t)((KT)*64 + swz8); \
  async_copy16(LDSP(BUF, 1) + rb0_*128, gb0_); \
  async_copy16(LDSP(BUF, 1) + rb1_*128, gb1_); \
} while (0)

#define RDA4(BUF, MH) do { \
  _Pragma("unroll") \
  for (int i2_ = 0; i2_ < 4; ++i2_) { \
    const char* rp_ = LDSP(BUF, 0) + (wr*128 + (MH)*64 + i2_*16 + fm) * 128; \
    a[i2_][0] = *(const bf16x8*)(rp_ + (((kqi    ) ^ fm7) << 4)); \
    a[i2_][1] = *(const bf16x8*)(rp_ + (((4 + kqi) ^ fm7) << 4)); \
  } \
} while (0)

#define RDB4(BUF, NH, DST) do { \
  _Pragma("unroll") \
  for (int j2_ = 0; j2_ < 2; ++j2_) { \
    const char* rp_ = LDSP(BUF, 1) + (wc*64 + (NH)*32 + j2_*16 + fm) * 128; \
    DST[j2_][0] = *(const bf16x8*)(rp_ + (((kqi    ) ^ fm7) << 4)); \
    DST[j2_][1] = *(const bf16x8*)(rp_ + (((4 + kqi) ^ fm7) << 4)); \
  } \
} while (0)

#define QMFMA(MH, NH, BB) do { \
  __builtin_amdgcn_s_setprio(1); \
  _Pragma("unroll") \
  for (int i2_ = 0; i2_ < 4; ++i2_) { \
    _Pragma("unroll") \
    for (int j2_ = 0; j2_ < 2; ++j2_) { \
      acc[(MH)*4 + i2_][(NH)*2 + j2_] = __builtin_amdgcn_mfma_f32_16x16x32_bf16( \
          a[i2_][0], BB[j2_][0], acc[(MH)*4 + i2_][(NH)*2 + j2_], 0, 0, 0); \
      acc[(MH)*4 + i2_][(NH)*2 + j2_] = __builtin_amdgcn_mfma_f32_16x16x32_bf16( \
          a[i2_][1], BB[j2_][1], acc[(MH)*4 + i2_][(NH)*2 + j2_], 0, 0, 0); \
    } \
  } \
  __builtin_amdgcn_s_setprio(0); \
} while (0)

#define ITER(TT, LAST) do { \
  RDA4(0, 0); RDB4(0, 0, b0); \
  STAGE_B(1, 1, (TT) + 1); \
  PHB(); QMFMA(0, 0, b0); PHB(); \
  RDB4(0, 1, b1); \
  if (!(LAST)) STAGE_A(0, 0, (TT) + 2); \
  PHB(); QMFMA(0, 1, b1); PHB(); \
  RDA4(0, 1); \
  if (!(LAST)) STAGE_B(0, 0, (TT) + 2); \
  PHB(); QMFMA(1, 0, b0); PHB(); \
  if (!(LAST)) { STAGE_A(0, 1, (TT) + 2); WAIT_VMCNT(6); } else { WAIT_VMCNT(0); } \
  PHB(); QMFMA(1, 1, b1); PHB(); \
  RDA4(1, 0); RDB4(1, 0, b0); \
  if (!(LAST)) STAGE_B(0, 1, (TT) + 2); \
  PHB(); QMFMA(0, 0, b0); PHB(); \
  RDB4(1, 1, b1); \
  if (!(LAST)) STAGE_A(1, 0, (TT) + 3); \
  PHB(); QMFMA(0, 1, b1); PHB(); \
  RDA4(1, 1); \
  if (!(LAST)) STAGE_B(1, 0, (TT) + 3); \
  PHB(); QMFMA(1, 0, b0); PHB(); \
  if (!(LAST)) { STAGE_A(1, 1, (TT) + 3); WAIT_VMCNT(6); } else { WAIT_VMCNT(0); } \
  PHB(); QMFMA(1, 1, b1); PHB(); \
} while (0)

__global__ __launch_bounds__(512, 2) void gemm256(
    const bf16* __restrict__ Ag, const bf16* __restrict__ Bg,
    float* __restrict__ C, int M, int N, int K, int ntm)
{
    (void)M;
    __shared__ __align__(16) char smem[131072];   // [buf][A/B] 4 x 32KB

    const int cpx  = gridDim.x >> 3;
    const int bid  = blockIdx.x;
    const int wgid = (bid & 7) * cpx + (bid >> 3);
    const int m0 = (wgid % ntm) << 8;
    const int n0 = (wgid / ntm) << 8;

    const int t    = threadIdx.x;
    const int wave = t >> 6, lane = t & 63;
    const int wr = wave >> 2, wc = wave & 3;     // 2 x 4 wave grid
    const int fm  = lane & 15, fm7 = lane & 7;
    const int kqi = lane >> 4;
    const int swz8 = (((lane & 7) ^ ((lane >> 3) & 7)) << 3);
    const int nkt = K >> 6;

    f32x4 acc[8][4];
    #pragma unroll
    for (int i = 0; i < 8; ++i)
        #pragma unroll
        for (int j = 0; j < 4; ++j)
            acc[i][j] = {0.f, 0.f, 0.f, 0.f};

    bf16x8 a[4][2], b0[2][2], b1[2][2];

    STAGE_A(0, 0, 0); STAGE_A(0, 1, 0); STAGE_B(0, 0, 0); STAGE_B(0, 1, 0);
    WAIT_VMCNT(4);
    STAGE_A(1, 0, 1); STAGE_A(1, 1, 1); STAGE_B(1, 0, 1);
    WAIT_VMCNT(6);
    PHB();

    int tt = 0;
    #pragma unroll 1
    for (; tt + 2 < nkt; tt += 2) { ITER(tt, false); }
    ITER(tt, true);

    const int lr = (lane >> 4) * 4;
    const int lc = lane & 15;
    #pragma unroll
    for (int i = 0; i < 8; ++i) {
        #pragma unroll
        for (int j = 0; j < 4; ++j) {
            const size_t base = (size_t)(m0 + wr*128 + i*16 + lr) * N
                              + (size_t)(n0 + wc*64 + j*16 + lc);
            #pragma unroll
            for (int r = 0; r < 4; ++r)
                C[base + (size_t)r * N] = acc[i][j][r];
        }
    }
}

// ---------------------------------------------------------------------------
// GEMM: C(M,N) = A(M,K) * B(N,K)^T.  A,B bf16 row-major (lda = leading dim),
// K = depth this launch processes.  blockIdx.y = split-K slice: reads cols
// [z*K, (z+1)*K), writes partial to C + z*M*N.
// EPI: 0 = store, 2 = C = softplus(v + bias[col]).
template<int EPI>
__global__ __launch_bounds__(256) void gemm_bt(
    const bf16* __restrict__ A, const bf16* __restrict__ B,
    float* __restrict__ C, const float* __restrict__ bias,
    int M, int N, int K, int lda, int ntm)
{
    __shared__ bf16 sA[128 * 32];
    __shared__ bf16 sB[128 * 32];
    const int bid  = blockIdx.x;
    const int m0   = (bid % ntm) * 128;
    const int n0   = (bid / ntm) * 128;
    const int koff = blockIdx.y * K;
    const int t    = threadIdx.x;
    const int wave = t >> 6;
    const int lane = t & 63;
    const int r0 = wave * 16 + (lane >> 2);      // tile row 0..63
    const int c0 = (lane & 3) * 8;               // k element offset 0/8/16/24
    const int wm = (wave & 1) * 64;
    const int wn = (wave >> 1) * 64;
    const int fm = lane & 15;
    const int kq = (lane >> 4) * 8;

    f32x4 acc[4][4];
    #pragma unroll
    for (int i = 0; i < 4; ++i)
        #pragma unroll
        for (int j = 0; j < 4; ++j)
            acc[i][j] = {0.f, 0.f, 0.f, 0.f};

    int nr0 = n0 + r0;      if (nr0 > N - 1) nr0 = N - 1;
    int nr1 = n0 + 64 + r0; if (nr1 > N - 1) nr1 = N - 1;

    const bf16* gA0 = A + (size_t)(m0 + r0)      * lda + koff + c0;
    const bf16* gA1 = A + (size_t)(m0 + 64 + r0) * lda + koff + c0;
    const bf16* gB0 = B + (size_t)nr0 * lda + koff + c0;
    const bf16* gB1 = B + (size_t)nr1 * lda + koff + c0;
    char* lA0 = (char*)sA + wave * 1024;
    char* lA1 = (char*)sA + 4096 + wave * 1024;
    char* lB0 = (char*)sB + wave * 1024;
    char* lB1 = (char*)sB + 4096 + wave * 1024;

    C += (size_t)blockIdx.y * M * N;

    for (int k0 = 0; k0 < K; k0 += 32) {
        async_copy16(lA0, gA0 + k0);
        async_copy16(lA1, gA1 + k0);
        async_copy16(lB0, gB0 + k0);
        async_copy16(lB1, gB1 + k0);
        __syncthreads();

        bf16x8 af[4], bfr[4];
        #pragma unroll
        for (int i = 0; i < 4; ++i) {
            af[i]  = *(const bf16x8*)&sA[(wm + i * 16 + fm) * 32 + kq];
            bfr[i] = *(const bf16x8*)&sB[(wn + i * 16 + fm) * 32 + kq];
        }
        #pragma unroll
        for (int i = 0; i < 4; ++i)
            #pragma unroll
            for (int j = 0; j < 4; ++j)
                acc[i][j] = __builtin_amdgcn_mfma_f32_16x16x32_bf16(
                    af[i], bfr[j], acc[i][j], 0, 0, 0);
        __syncthreads();
    }

    const int lr = (lane >> 4) * 4;
    const int lc = lane & 15;
    #pragma unroll
    for (int i = 0; i < 4; ++i) {
        #pragma unroll
        for (int j = 0; j < 4; ++j) {
            const int col = n0 + wn + j * 16 + lc;
            if (col >= N) continue;
            #pragma unroll
            for (int r = 0; r < 4; ++r) {
                const int row = m0 + wm + i * 16 + lr + r;
                const size_t o = (size_t)row * N + col;
                float v = acc[i][j][r];
                if (EPI == 2) {
                    v += bias[col];
                    v = (v > 15.f) ? v : __logf(1.f + __expf(v));
                    C[o] = v;
                } else {
                    C[o] = v;
                }
            }
        }
    }
}

// ---------------------------------------------------------------------------
// Fused preamble (ONE launch):
//   blocks [0, NROWS):       embedding gather -> x, + rmsnorm -> xn
//   blocks [NROWS, grid):    grid-stride cvt of emb->bf16 and all weights
__global__ __launch_bounds__(256) void preamble_kernel(
    const int* __restrict__ ids, const float* __restrict__ emb,
    const float* __restrict__ norm_w,
    const float* __restrict__ ipw, const float* __restrict__ xpw,
    const float* __restrict__ dtw, const float* __restrict__ opw,
    bf16* __restrict__ emb_bf, bf16* __restrict__ wip, bf16* __restrict__ wxp,
    bf16* __restrict__ wdt, bf16* __restrict__ wop,
    float* __restrict__ x, bf16* __restrict__ xn)
{
    const int t = threadIdx.x;
    if (blockIdx.x < NROWS) {
        // ---- embedding gather + rmsnorm (row-local) ----
        const int row = blockIdx.x;
        const float* src = emb + (size_t)ids[row] * D_MODEL;
        float v0 = src[t], v1 = src[t + 256], v2 = src[t + 512];
        float* xr = x + (size_t)row * D_MODEL;
        xr[t] = v0; xr[t + 256] = v1; xr[t + 512] = v2;
        float s = v0 * v0 + v1 * v1 + v2 * v2;
        #pragma unroll
        for (int m = 1; m < 64; m <<= 1) s += __shfl_xor(s, m);
        __shared__ float red[4];
        if ((t & 63) == 0) red[t >> 6] = s;
        __syncthreads();
        s = red[0] + red[1] + red[2] + red[3];
        const float sc = rsqrtf(s * (1.f / 768.f) + 1e-5f);
        bf16* o = xn + (size_t)row * D_MODEL;
        o[t]       = __float2bfloat16(v0 * sc * norm_w[t]);
        o[t + 256] = __float2bfloat16(v1 * sc * norm_w[t + 256]);
        o[t + 512] = __float2bfloat16(v2 * sc * norm_w[t + 512]);
        return;
    }
    // ---- grid-stride conversions ----
    const int i0   = (blockIdx.x - NROWS) * 256 + t;
    const int strd = (gridDim.x - NROWS) * 256;
    // embedding f32 -> bf16, 8 elements per item
    for (int it = i0; it < VOCAB * D_MODEL / 8; it += strd) {
        const int i = it * 8;
        const float4 a = *(const float4*)(emb + i);
        const float4 b = *(const float4*)(emb + i + 4);
        bf8 o;
        o.v[0] = __float2bfloat16(a.x); o.v[1] = __float2bfloat16(a.y);
        o.v[2] = __float2bfloat16(a.z); o.v[3] = __float2bfloat16(a.w);
        o.v[4] = __float2bfloat16(b.x); o.v[5] = __float2bfloat16(b.y);
        o.v[6] = __float2bfloat16(b.z); o.v[7] = __float2bfloat16(b.w);
        *(bf8*)(emb_bf + i) = o;
    }
    // both layers' weights: [layer][ip 3072*768 | xp 80*1536 | dt pad | op]
    for (int it = i0; it < 2 * 3760128; it += strd) {
        int i = it;
        const int l = (i >= 3760128) ? 1 : 0;
        i -= l * 3760128;
        if (i < 3072 * 768) {
            wip[l * 3072 * 768 + i] = __float2bfloat16(ipw[l * 3072 * 768 + i]);
            continue;
        }
        i -= 3072 * 768;
        if (i < 80 * 1536) {
            wxp[l * 80 * 1536 + i] = __float2bfloat16(xpw[l * 80 * 1536 + i]);
            continue;
        }
        i -= 80 * 1536;
        if (i < 1536 * 64) {
            const int r = i >> 6, c = i & 63;
            wdt[l * 1536 * 64 + i] = __float2bfloat16(
                c < DT_RANK ? dtw[l * 1536 * DT_RANK + r * DT_RANK + c] : 0.f);
            continue;
        }
        i -= 1536 * 64;
        wop[l * 768 * 1536 + i] = __float2bfloat16(opw[l * 768 * 1536 + i]);
    }
}

// ---------------------------------------------------------------------------
// x_proj split-K reduce: xdbl = sum of 4 partial slices; also emits dtraw
// (delta cols 0..47 zero-padded to 64, bf16) -- fuses pad_dt.
__global__ __launch_bounds__(256) void reduce_xp_kernel(
    const float* __restrict__ p, float* __restrict__ xdbl,
    bf16* __restrict__ dtraw)
{
    const int i = blockIdx.x * 256 + threadIdx.x;   // < NROWS*80
    const float v = p[i] + p[i + 163840] + p[i + 327680] + p[i + 491520];
    xdbl[i] = v;
    const int r = i / 80, c = i - r * 80;
    if (c < 64)
        dtraw[(r << 6) + c] = __float2bfloat16(c < DT_RANK ? v : 0.f);
}

// ---------------------------------------------------------------------------
// out_proj split-K reduce + residual add into x + rmsnorm -> xn (bf16).
__global__ __launch_bounds__(256) void reduce_res_norm_kernel(
    const float* __restrict__ part, float* __restrict__ x,
    const float* __restrict__ w, bf16* __restrict__ out)
{
    const int row = blockIdx.x;
    const size_t base = (size_t)row * D_MODEL;
    const int t = threadIdx.x;
    float v0, v1, v2;
    {
        const size_t e0 = base + t, e1 = base + t + 256, e2 = base + t + 512;
        v0 = x[e0] + part[e0] + part[e0 + 1572864] + part[e0 + 3145728] + part[e0 + 4718592];
        v1 = x[e1] + part[e1] + part[e1 + 1572864] + part[e1 + 3145728] + part[e1 + 4718592];
        v2 = x[e2] + part[e2] + part[e2 + 1572864] + part[e2 + 3145728] + part[e2 + 4718592];
    }
    x[base + t]       = v0;
    x[base + t + 256] = v1;
    x[base + t + 512] = v2;
    float s = v0 * v0 + v1 * v1 + v2 * v2;
    #pragma unroll
    for (int m = 1; m < 64; m <<= 1) s += __shfl_xor(s, m);
    __shared__ float red[4];
    if ((t & 63) == 0) red[t >> 6] = s;
    __syncthreads();
    s = red[0] + red[1] + red[2] + red[3];
    const float sc = rsqrtf(s * (1.f / 768.f) + 1e-5f);
    bf16* o = out + base;
    o[t]       = __float2bfloat16(v0 * sc * w[t]);
    o[t + 256] = __float2bfloat16(v1 * sc * w[t + 256]);
    o[t + 512] = __float2bfloat16(v2 * sc * w[t + 512]);
}

// ---------------------------------------------------------------------------
// causal depthwise conv (k=4) + bias + silu; writes f32 (for scan) + bf16 (GEMM A)
__global__ __launch_bounds__(256) void conv_silu_kernel(
    const float* __restrict__ xr, const float* __restrict__ cw,
    const float* __restrict__ cb, float* __restrict__ uf,
    bf16* __restrict__ ub)
{
    const int idx = blockIdx.x * 256 + threadIdx.x;   // < 2048*1536
    const int di  = idx % D_INNER;
    const int row = idx / D_INNER;
    const int l   = row & (SEQ - 1);
    float acc = cb[di];
    #pragma unroll
    for (int j = 0; j < 4; ++j) {
        const int ll = l - 3 + j;
        if (ll >= 0)
            acc += cw[di * 4 + j] * xr[(size_t)(row - 3 + j) * 3072 + di];
    }
    const float s = acc / (1.f + __expf(-acc));
    uf[idx] = s;
    ub[idx] = __float2bfloat16(s);
}

// ---------------------------------------------------------------------------
// Chunked selective scan, LCHUNK=32 / NCHUNK=32.
__global__ __launch_bounds__(256) void scan_pass1(
    const float* __restrict__ delta, const float* __restrict__ u,
    const float* __restrict__ x_dbl, const float* __restrict__ A_log,
    float* __restrict__ P, float* __restrict__ H)
{
    const int n  = threadIdx.x & 15;
    const int g  = threadIdx.x >> 4;
    const int ch = blockIdx.x * 16 + g;      // 0..3071
    const int k  = blockIdx.y;               // chunk
    const int b  = ch / D_INNER;
    const int di = ch % D_INNER;
    const int t0 = k * LCHUNK;

    const float An = -__expf(A_log[di * D_STATE + n]);
    const float* drow = delta + ((size_t)b * SEQ + t0) * D_INNER + di;
    const float* urow = u     + ((size_t)b * SEQ + t0) * D_INNER + di;
    const float* xdr  = x_dbl + ((size_t)b * SEQ + t0) * 80;

    float h = 0.f, ap = 1.f;
    #pragma unroll
    for (int t = 0; t < LCHUNK; ++t) {
        const float dv = drow[t * D_INNER];
        const float uv = urow[t * D_INNER];
        const float Bv = xdr[t * 80 + 48 + n];
        const float a  = __expf(dv * An);
        h = a * h + (dv * Bv) * uv;
        ap *= a;
    }
    const size_t o = (size_t)k * CHST + ch * 16 + n;
    P[o] = ap;
    H[o] = h;
}

__global__ __launch_bounds__(256) void scan_pass2(
    const float* __restrict__ P, const float* __restrict__ H,
    float* __restrict__ Hin)
{
    const int id = blockIdx.x * 256 + threadIdx.x;   // < CHST
    float h = 0.f;
    #pragma unroll
    for (int k = 0; k < NCHUNK; ++k) {
        const size_t o = (size_t)k * CHST + id;
        Hin[o] = h;
        h = P[o] * h + H[o];
    }
}

__global__ __launch_bounds__(256) void scan_pass3(
    const float* __restrict__ delta, const float* __restrict__ u,
    const float* __restrict__ x_dbl, const float* __restrict__ xr,
    const float* __restrict__ A_log, const float* __restrict__ Dp,
    const float* __restrict__ Hin, bf16* __restrict__ yb)
{
    const int n  = threadIdx.x & 15;
    const int g  = threadIdx.x >> 4;
    const int ch = blockIdx.x * 16 + g;
    const int k  = blockIdx.y;
    const int b  = ch / D_INNER;
    const int di = ch % D_INNER;
    const int t0 = k * LCHUNK;

    const float An = -__expf(A_log[di * D_STATE + n]);
    const float Dv = Dp[di];
    const float* drow = delta + ((size_t)b * SEQ + t0) * D_INNER + di;
    const float* urow = u     + ((size_t)b * SEQ + t0) * D_INNER + di;
    const float* rrow = xr + ((size_t)b * SEQ + t0) * 3072 + D_INNER + di;
    const float* xdr  = x_dbl + ((size_t)b * SEQ + t0) * 80;
    bf16* yrow = yb + ((size_t)b * SEQ + t0) * D_INNER + di;

    float h = Hin[(size_t)k * CHST + ch * 16 + n];
    #pragma unroll
    for (int t = 0; t < LCHUNK; ++t) {
        const float dv = drow[t * D_INNER];
        const float uv = urow[t * D_INNER];
        const float Bv = xdr[t * 80 + 48 + n];
        const float Cv = xdr[t * 80 + 64 + n];
        const float a  = __expf(dv * An);
        h = a * h + (dv * Bv) * uv;
        float p = h * Cv;
        p += __shfl_xor(p, 1);
        p += __shfl_xor(p, 2);
        p += __shfl_xor(p, 4);
        p += __shfl_xor(p, 8);
        if (n == 0) {
            float y = p + uv * Dv;
            const float r = rrow[t * 3072];
            y *= r / (1.f + __expf(-r));       // * silu(res)
            yrow[t * D_INNER] = __float2bfloat16(y);
        }
    }
}

// ---------------------------------------------------------------------------
extern "C" void kernel_launch(void* const* d_in, const int* in_sizes, int n_in,
                              void* d_out, int out_size, void* d_ws, size_t ws_size,
                              hipStream_t stream)
{
    const int*   ids    = (const int*)  d_in[0];
    const float* emb    = (const float*)d_in[1];
    const float* norm_w = (const float*)d_in[2];
    const float* ipw    = (const float*)d_in[3];
    const float* cw     = (const float*)d_in[4];
    const float* cb     = (const float*)d_in[5];
    const float* xpw    = (const float*)d_in[6];
    const float* dtw    = (const float*)d_in[7];
    const float* dtb    = (const float*)d_in[8];
    const float* alog   = (const float*)d_in[9];
    const float* Dp     = (const float*)d_in[10];
    const float* opw    = (const float*)d_in[11];
    const float* nfw    = (const float*)d_in[12];
    float* out = (float*)d_out;

    // -------- workspace layout (~87 MB) --------
    char* ws = (char*)d_ws;
    bf16*  emb_bf = (bf16*)ws;  ws += (size_t)VOCAB * D_MODEL * 2;
    float* x      = (float*)ws; ws += (size_t)NROWS * D_MODEL * 4;
    bf16*  xn     = (bf16*)ws;  ws += (size_t)NROWS * D_MODEL * 2;
    bf16*  ub     = (bf16*)ws;  ws += (size_t)NROWS * D_INNER * 2;
    float* xdbl   = (float*)ws; ws += (size_t)NROWS * 80 * 4;
    bf16*  dtraw  = (bf16*)ws;  ws += (size_t)NROWS * 64 * 2;
    bf16*  yb     = (bf16*)ws;  ws += (size_t)NROWS * D_INNER * 2;
    bf16*  wip    = (bf16*)ws;  ws += (size_t)2 * 3072 * 768 * 2;
    bf16*  wxp    = (bf16*)ws;  ws += (size_t)2 * 80 * 1536 * 2;
    bf16*  wdt    = (bf16*)ws;  ws += (size_t)2 * 1536 * 64 * 2;
    bf16*  wop    = (bf16*)ws;  ws += (size_t)2 * 768 * 1536 * 2;

    // -------- big transients live in d_out (262 MB), overwritten by logits --------
    char* ob = (char*)d_out;
    float* xr    = (float*)ob;  ob += (size_t)NROWS * 3072 * 4;      // 25.2 MB
    float* uf    = (float*)ob;  ob += (size_t)NROWS * D_INNER * 4;   // 12.6 MB
    float* delta = (float*)ob;  ob += (size_t)NROWS * D_INNER * 4;   // 12.6 MB
    float* Pbuf  = (float*)ob;  ob += (size_t)NCHUNK * CHST * 4;     //  6.3 MB
    float* Hbuf  = (float*)ob;  ob += (size_t)NCHUNK * CHST * 4;     //  6.3 MB
    float* Hin   = (float*)ob;  ob += (size_t)NCHUNK * CHST * 4;     //  6.3 MB
    float* xpart = (float*)ob;  ob += (size_t)4 * NROWS * 80 * 4;    //  2.6 MB
    float* opart = (float*)ob;  ob += (size_t)4 * NROWS * D_MODEL * 4; // 25.2 MB

    // ---- fused preamble: cvt emb + cvt weights + embed + first rmsnorm ----
    preamble_kernel<<<NROWS + 4096, 256, 0, stream>>>(
        ids, emb, norm_w, ipw, xpw, dtw, opw,
        emb_bf, wip, wxp, wdt, wop, x, xn);

    for (int l = 0; l < 2; ++l) {
        // in_proj: (2048x768)(3072x768)^T -> xr
        gemm_bt<0><<<16 * 24, 256, 0, stream>>>(
            xn, wip + (size_t)l * 3072 * 768, xr, nullptr,
            NROWS, 3072, D_MODEL, D_MODEL, 16);
        conv_silu_kernel<<<NROWS * D_INNER / 256, 256, 0, stream>>>(
            xr, cw + (size_t)l * D_INNER * 4, cb + (size_t)l * D_INNER, uf, ub);
        // x_proj: (2048x1536)(80x1536)^T, split-K x4 -> partials
        gemm_bt<0><<<dim3(16, 4), 256, 0, stream>>>(
            ub, wxp + (size_t)l * 80 * 1536, xpart, nullptr,
            NROWS, 80, 384, D_INNER, 16);
        reduce_xp_kernel<<<NROWS * 80 / 256, 256, 0, stream>>>(
            xpart, xdbl, dtraw);                         // + fused pad_dt
        // dt_proj + softplus: (2048x64)(1536x64)^T -> delta
        gemm_bt<2><<<16 * 12, 256, 0, stream>>>(
            dtraw, wdt + (size_t)l * 1536 * 64, delta,
            dtb + (size_t)l * D_INNER, NROWS, D_INNER, 64, 64, 16);
        // chunked selective scan
        scan_pass1<<<dim3(192, NCHUNK), 256, 0, stream>>>(
            delta, uf, xdbl, alog + (size_t)l * D_INNER * D_STATE, Pbuf, Hbuf);
        scan_pass2<<<CHST / 256, 256, 0, stream>>>(Pbuf, Hbuf, Hin);
        scan_pass3<<<dim3(192, NCHUNK), 256, 0, stream>>>(
            delta, uf, xdbl, xr, alog + (size_t)l * D_INNER * D_STATE,
            Dp + (size_t)l * D_INNER, Hin, yb);
        // out_proj: (2048x1536)(768x1536)^T, split-K x4 -> partials
        gemm_bt<0><<<dim3(96, 4), 256, 0, stream>>>(
            yb, wop + (size_t)l * 768 * 1536, opart, nullptr,
            NROWS, D_MODEL, 384, D_INNER, 16);
        // reduce + residual into x + rmsnorm for next stage
        reduce_res_norm_kernel<<<NROWS, 256, 0, stream>>>(
            opart, x, (l == 0) ? (norm_w + D_MODEL) : nfw, xn);
    }

    // logits: (2048x768)(32000x768)^T -> out  [256^2 8-phase kernel, 1000 blocks]
    gemm256<<<8 * 125, 512, 0, stream>>>(xn, emb_bf, out,
                                         NROWS, VOCAB, D_MODEL, 8);
}